// Round 10
// baseline (87.347 us; speedup 1.0000x reference)
//
#include <hip/hip_runtime.h>

#define SEQ   8192
#define EMB   64
#define NLEAF 8192
#define KQ    2048          // K per gemm block (quarter of SEQ)
#define KT    128           // K per tile (512B per row -- 2x run length)
#define NT    (KQ / KT)     // 16 tiles

typedef __attribute__((ext_vector_type(4))) float        f32x4;
typedef __attribute__((ext_vector_type(4))) unsigned int u32x4;

// ---- bf16 RNE pack: pair (x,y) -> [bf16(x) | bf16(y)<<16] ----
__device__ __forceinline__ unsigned rne_pair(float x, float y) {
    const unsigned ux = __float_as_uint(x), uy = __float_as_uint(y);
    const unsigned rx = (ux + 0x7fffu + ((ux >> 16) & 1u)) >> 16;
    const unsigned ry = (uy + 0x7fffu + ((uy >> 16) & 1u)) & 0xffff0000u;
    return rx | ry;
}

__device__ __forceinline__ void mfma16(f32x4& d, const u32x4 a, const u32x4 b) {
    asm("v_mfma_f32_16x16x32_bf16 %0, %1, %2, %0" : "+v"(d) : "v"(a), "v"(b));
}

// async global->LDS, 16B per lane; offset immediate ALWAYS 0 (R4 lesson).
#define GLDS16(gp, lp) \
    __builtin_amdgcn_global_load_lds( \
        (const __attribute__((address_space(1))) void*)(gp), \
        (__attribute__((address_space(3))) void*)(lp), 16, 0, 0)

// ============================================================================
// K0: W [64][8192] f32 -> bf16 RNE per-tile images (16KB each: 64 rows x
// 256B = 16 chunks; stored chunk chsw holds content chunk chsw ^ (row&7)).
// Linear store: byte addr = gid*16. grid 256 x 256.
// ============================================================================
__global__ __launch_bounds__(256) void k_cvtW(const float* __restrict__ W,
                                              unsigned* __restrict__ Wt)
{
    const int gid  = blockIdx.x * 256 + threadIdx.x;   // 65536 = 4*16*64*16
    const int chsw = gid & 15;
    const int row  = (gid >> 4) & 63;
    const int t    = (gid >> 10) & 15;
    const int q    = gid >> 14;
    const int c    = chsw ^ (row & 7);                 // XOR hits low 3 bits only
    const float* src = W + (size_t)row * SEQ + q * KQ + t * KT + c * 8;
    const f32x4 a = *(const f32x4*)(src);
    const f32x4 b = *(const f32x4*)(src + 4);
    u32x4 v;
    v[0] = rne_pair(a.x, a.y);
    v[1] = rne_pair(a.z, a.w);
    v[2] = rne_pair(b.x, b.y);
    v[3] = rne_pair(b.z, b.w);
    *(u32x4*)(Wt + (size_t)gid * 4) = v;
}

// ============================================================================
// K1: leaf embedding GEMM, bf16 RNE MFMA, K-quarter partials.
// R9 skeleton, KT=128 (ONE variable vs R9): A global->VGPR (2 static reg
// sets of 8 x f32x4; wave owns 16 rows; 512B contiguous per row per tile),
// W in LDS via glds (3 x 16KB buffers). Steady-state wait vmcnt(12):
// outstanding = [W(t) 4, A(t) 8, W(t+1) 4, A(t+1) 8] = 24 -> retires tile t.
// 16 phases, 1 barrier each. grid 512, block 256 (4 waves), 2 blocks/CU.
// ============================================================================
__global__ __launch_bounds__(256, 2) void k_gemm(
        const float* __restrict__ A, const char* __restrict__ Wt,
        float* __restrict__ P)
{
    __shared__ char sW[3][16384];           // bf16 W tile images

    const int tid  = threadIdx.x;
    const int lane = tid & 63;
    const int wid  = tid >> 6;

    const int g     = blockIdx.x >> 2;   // leaf group (64 leaves)
    const int q     = blockIdx.x & 3;    // k quarter
    const int gl0   = g * 64;
    const int kbase = q * KQ;

    const int fr = lane & 15;
    const int fq = lane >> 4;

    // per-lane A pointer: row = gl0 + wid*16 + fr, k offset fq*8
    const float* pA = A + (size_t)(gl0 + wid * 16 + fr) * SEQ + kbase + fq * 8;
    // W staging: wave w covers bytes [4w KB, 4w+4 KB) of the 16KB image
    const char* pW = Wt + (size_t)(q * 16) * 16384 + wid * 4096 + lane * 16;

    f32x4 acc0 = {0.f, 0.f, 0.f, 0.f};
    f32x4 acc1 = {0.f, 0.f, 0.f, 0.f};
    f32x4 acc2 = {0.f, 0.f, 0.f, 0.f};
    f32x4 acc3 = {0.f, 0.f, 0.f, 0.f};

    // two static A register sets (rule #20: all indices compile-time)
    f32x4 a0c0, a0c1, a0c2, a0c3, a0c4, a0c5, a0c6, a0c7;
    f32x4 a1c0, a1c1, a1c2, a1c3, a1c4, a1c5, a1c6, a1c7;

#define STAGEW(bi_) do { \
    char* wdst = (char*)&sW[bi_][0] + wid * 4096; \
    GLDS16(pW,        wdst); \
    GLDS16(pW + 1024, wdst + 1024); \
    GLDS16(pW + 2048, wdst + 2048); \
    GLDS16(pW + 3072, wdst + 3072); \
    pW += 16384; \
} while (0)

#define LOADA(c0_, c1_, c2_, c3_, c4_, c5_, c6_, c7_) do { \
    c0_ = *(const f32x4*)(pA);       c1_ = *(const f32x4*)(pA + 4); \
    c2_ = *(const f32x4*)(pA + 32);  c3_ = *(const f32x4*)(pA + 36); \
    c4_ = *(const f32x4*)(pA + 64);  c5_ = *(const f32x4*)(pA + 68); \
    c6_ = *(const f32x4*)(pA + 96);  c7_ = *(const f32x4*)(pA + 100); \
    pA += KT; \
} while (0)

#define SUB(lo_, hi_, j_, bi_) do { \
    u32x4 af; \
    af[0] = rne_pair(lo_.x, lo_.y); \
    af[1] = rne_pair(lo_.z, lo_.w); \
    af[2] = rne_pair(hi_.x, hi_.y); \
    af[3] = rne_pair(hi_.z, hi_.w); \
    const char* bufW_ = &sW[bi_][0]; \
    const int baddr = fr * 256 + 16 * ((4 * (j_) + fq) ^ (fr & 7)); \
    mfma16(acc0, af, *(const u32x4*)(bufW_ + baddr)); \
    mfma16(acc1, af, *(const u32x4*)(bufW_ +  4096 + baddr)); \
    mfma16(acc2, af, *(const u32x4*)(bufW_ +  8192 + baddr)); \
    mfma16(acc3, af, *(const u32x4*)(bufW_ + 12288 + baddr)); \
} while (0)

#define PHASE(t_, c0_, c1_, c2_, c3_, c4_, c5_, c6_, c7_) do { \
    if ((t_) < NT - 1) asm volatile("s_waitcnt vmcnt(12)" ::: "memory"); \
    else               asm volatile("s_waitcnt vmcnt(0)" ::: "memory"); \
    __builtin_amdgcn_s_barrier(); \
    __builtin_amdgcn_sched_barrier(0); \
    const bool more2_ = ((t_) + 2 < NT); \
    if (more2_) STAGEW(bfut); \
    SUB(c0_, c1_, 0, bcur); \
    SUB(c2_, c3_, 1, bcur); \
    SUB(c4_, c5_, 2, bcur); \
    SUB(c6_, c7_, 3, bcur); \
    asm volatile("s_waitcnt lgkmcnt(0)" ::: "memory"); \
    if (more2_) LOADA(c0_, c1_, c2_, c3_, c4_, c5_, c6_, c7_); \
    const int tmp_ = bcur; bcur = bnxt; bnxt = bfut; bfut = tmp_; \
} while (0)

    // prologue: W(0), A(0), W(1), A(1) -> 24 outstanding per wave
    STAGEW(0);
    LOADA(a0c0, a0c1, a0c2, a0c3, a0c4, a0c5, a0c6, a0c7);
    STAGEW(1);
    LOADA(a1c0, a1c1, a1c2, a1c3, a1c4, a1c5, a1c6, a1c7);

    int bcur = 0, bnxt = 1, bfut = 2;
    #pragma unroll 1
    for (int i = 0; i < NT / 2; ++i) {
        PHASE(2 * i,     a0c0, a0c1, a0c2, a0c3, a0c4, a0c5, a0c6, a0c7);
        PHASE(2 * i + 1, a1c0, a1c1, a1c2, a1c3, a1c4, a1c5, a1c6, a1c7);
    }

#undef STAGEW
#undef LOADA
#undef SUB
#undef PHASE

    // ---- store partials: wave w rows 16w + fq*4 + r, col n*16 + fr ----
    float* Pq = P + (size_t)q * NLEAF * EMB;
    const int row0 = gl0 + wid * 16 + fq * 4;
    #pragma unroll
    for (int r = 0; r < 4; ++r) {
        Pq[(size_t)(row0 + r) * EMB +  0 + fr] = acc0[r];
        Pq[(size_t)(row0 + r) * EMB + 16 + fr] = acc1[r];
        Pq[(size_t)(row0 + r) * EMB + 32 + fr] = acc2[r];
        Pq[(size_t)(row0 + r) * EMB + 48 + fr] = acc3[r];
    }
}

// ============================================================================
// Tree (R5-verbatim champion tail). fp32 exact.
// ============================================================================
__device__ __forceinline__ void load_Wt(float (*Wt)[132],
                                        const float* __restrict__ WW, int tid) {
    const int e  = tid >> 2;
    const int c0 = (tid & 3) * 32;
    #pragma unroll
    for (int j = 0; j < 32; j += 4)
        *(f32x4*)&Wt[e][c0 + j] = *(const f32x4*)&WW[e * 128 + c0 + j];
}

__device__ __forceinline__ float hsum4(const f32x4 a) {
    return a.x + a.y + a.z + a.w;
}

__device__ __forceinline__ float* tree_levels(float* bufA, float* bufB,
        const float (*Wt)[132], float wb, int n0, int nlv, int tid)
{
    const int lane = tid & 63;
    const int wid  = tid >> 6;
    float* src = bufA;
    float* dst = bufB;
    int n = n0;
    for (int lvl = 0; lvl < nlv; ++lvl) {
        const int nodes = n >> 1;
        for (int base = wid * 4; base < nodes; base += 16) {
            const int cnt = (nodes - base < 4) ? (nodes - base) : 4;
            if (cnt == 4) {
                f32x4 ac0 = {0.f,0.f,0.f,0.f}, ac1 = ac0, ac2 = ac0, ac3 = ac0;
                const float* x0 = src + (2 * (base + 0)) * 68;
                const float* x1 = src + (2 * (base + 1)) * 68;
                const float* x2 = src + (2 * (base + 2)) * 68;
                const float* x3 = src + (2 * (base + 3)) * 68;
                #pragma unroll
                for (int j = 0; j < 32; ++j) {
                    const f32x4 w4 = *(const f32x4*)&Wt[lane][4 * j];
                    const int off = (j < 16) ? (4 * j) : (68 + 4 * (j - 16));
                    ac0 += w4 * *(const f32x4*)(x0 + off);
                    ac1 += w4 * *(const f32x4*)(x1 + off);
                    ac2 += w4 * *(const f32x4*)(x2 + off);
                    ac3 += w4 * *(const f32x4*)(x3 + off);
                }
                dst[(base + 0) * 68 + lane] = fmaxf(wb + hsum4(ac0), 0.f);
                dst[(base + 1) * 68 + lane] = fmaxf(wb + hsum4(ac1), 0.f);
                dst[(base + 2) * 68 + lane] = fmaxf(wb + hsum4(ac2), 0.f);
                dst[(base + 3) * 68 + lane] = fmaxf(wb + hsum4(ac3), 0.f);
            } else {
                for (int u = 0; u < cnt; ++u) {
                    f32x4 ac = {0.f, 0.f, 0.f, 0.f};
                    const float* x = src + (2 * (base + u)) * 68;
                    #pragma unroll
                    for (int j = 0; j < 32; ++j) {
                        const f32x4 w4 = *(const f32x4*)&Wt[lane][4 * j];
                        const int off = (j < 16) ? (4 * j) : (68 + 4 * (j - 16));
                        ac += w4 * *(const f32x4*)(x + off);
                    }
                    dst[(base + u) * 68 + lane] = fmaxf(wb + hsum4(ac), 0.f);
                }
            }
        }
        __syncthreads();
        float* tswp = src; src = dst; dst = tswp;
        n = nodes;
    }
    return src;   // root row after final swap
}

// K2: combine 4 K-quarter partials + bias + relu, then tree levels 1..5.
__global__ __launch_bounds__(256) void k_tree32(const float* __restrict__ P,
        const float* __restrict__ eb, const float* __restrict__ WW,
        const float* __restrict__ Wb, float* __restrict__ roots)
{
    __shared__ float hA[32][68];
    __shared__ float hB[16][68];
    __shared__ float Wt[64][132];
    const int tid = threadIdx.x;
    const int b   = blockIdx.x;
    load_Wt(Wt, WW, tid);
    {
        const int lf = tid >> 3;
        const int e0 = (tid & 7) * 8;
        const size_t base = (size_t)(b * 32 + lf) * EMB + e0;
        f32x4 s0 = *(const f32x4*)&P[base];
        f32x4 s1 = *(const f32x4*)&P[base + 4];
        s0 += *(const f32x4*)&P[(size_t)1 * NLEAF * EMB + base];
        s1 += *(const f32x4*)&P[(size_t)1 * NLEAF * EMB + base + 4];
        s0 += *(const f32x4*)&P[(size_t)2 * NLEAF * EMB + base];
        s1 += *(const f32x4*)&P[(size_t)2 * NLEAF * EMB + base + 4];
        s0 += *(const f32x4*)&P[(size_t)3 * NLEAF * EMB + base];
        s1 += *(const f32x4*)&P[(size_t)3 * NLEAF * EMB + base + 4];
        s0 += *(const f32x4*)&eb[e0];
        s1 += *(const f32x4*)&eb[e0 + 4];
        s0.x = fmaxf(s0.x, 0.f); s0.y = fmaxf(s0.y, 0.f);
        s0.z = fmaxf(s0.z, 0.f); s0.w = fmaxf(s0.w, 0.f);
        s1.x = fmaxf(s1.x, 0.f); s1.y = fmaxf(s1.y, 0.f);
        s1.z = fmaxf(s1.z, 0.f); s1.w = fmaxf(s1.w, 0.f);
        *(f32x4*)&hA[lf][e0]     = s0;
        *(f32x4*)&hA[lf][e0 + 4] = s1;
    }
    const float wb = Wb[tid & 63];
    __syncthreads();
    float* root = tree_levels(&hA[0][0], &hB[0][0], Wt, wb, 32, 5, tid);
    if (tid < 64) roots[b * 64 + tid] = root[tid];
}

// K3a: 16 roots -> 1 (levels 6..9). grid 16.
__global__ __launch_bounds__(256) void k_tree16(const float* __restrict__ in,
        const float* __restrict__ WW, const float* __restrict__ Wb,
        float* __restrict__ outv)
{
    __shared__ float hA[32][68];
    __shared__ float hB[16][68];
    __shared__ float Wt[64][132];
    const int tid = threadIdx.x;
    load_Wt(Wt, WW, tid);
    {
        const int r  = tid >> 4;
        const int e0 = (tid & 15) * 4;
        *(f32x4*)&hA[r][e0] =
            *(const f32x4*)&in[(size_t)(blockIdx.x * 16 + r) * EMB + e0];
    }
    const float wb = Wb[tid & 63];
    __syncthreads();
    float* root = tree_levels(&hA[0][0], &hB[0][0], Wt, wb, 16, 4, tid);
    if (tid < 64) outv[blockIdx.x * 64 + tid] = root[tid];
}

// K3b: 16 -> 1 (levels 10..13) + projection. grid 1.
__global__ __launch_bounds__(256) void k_root(const float* __restrict__ in,
        const float* __restrict__ WW, const float* __restrict__ Wb,
        const float* __restrict__ pW, const float* __restrict__ pb,
        float* __restrict__ out)
{
    __shared__ float hA[32][68];
    __shared__ float hB[16][68];
    __shared__ float Wt[64][132];
    const int tid = threadIdx.x;
    load_Wt(Wt, WW, tid);
    {
        const int r  = tid >> 4;
        const int e0 = (tid & 15) * 4;
        *(f32x4*)&hA[r][e0] = *(const f32x4*)&in[(size_t)r * EMB + e0];
    }
    const float wb = Wb[tid & 63];
    __syncthreads();
    float* root = tree_levels(&hA[0][0], &hB[0][0], Wt, wb, 16, 4, tid);
    if (tid < 64) {
        const float hv = root[tid];
        float t0 = hv * pW[tid];
        float t1 = hv * pW[64 + tid];
        #pragma unroll
        for (int off = 32; off > 0; off >>= 1) {
            t0 += __shfl_down(t0, off);
            t1 += __shfl_down(t1, off);
        }
        if (tid == 0) { out[0] = t0 + pb[0]; out[1] = t1 + pb[1]; }
    }
}

extern "C" void kernel_launch(void* const* d_in, const int* in_sizes, int n_in,
                              void* d_out, int out_size, void* d_ws, size_t ws_size,
                              hipStream_t stream)
{
    const float* A  = (const float*)d_in[0];   // leaf_seqs [8192][8192]
    const float* eW = (const float*)d_in[1];   // emb_W     [64][8192]
    const float* eb = (const float*)d_in[2];   // emb_b     [64]
    const float* WW = (const float*)d_in[3];   // W_W       [64][128]
    const float* Wb = (const float*)d_in[4];   // W_b       [64]
    const float* pW = (const float*)d_in[5];   // proj_W    [2][64]
    const float* pb = (const float*)d_in[6];   // proj_b    [2]
    float* out = (float*)d_out;

    float* P     = (float*)d_ws;                       // [4][8192][64] f32 = 8MB
    float* roots = P + (size_t)4 * NLEAF * EMB;        // [256][64]
    float* l9    = roots + 256 * EMB;                  // [16][64]
    char*  Wtil  = (char*)d_ws + (size_t)16 * 1024 * 1024;  // 1MB bf16 tile imgs

    k_cvtW  <<<dim3(256), dim3(256), 0, stream>>>(eW, (unsigned*)Wtil);
    k_gemm  <<<dim3(512), dim3(256), 0, stream>>>(A, Wtil, P);
    k_tree32<<<dim3(256), dim3(256), 0, stream>>>(P, eb, WW, Wb, roots);
    k_tree16<<<dim3(16),  dim3(256), 0, stream>>>(roots, WW, Wb, l9);
    k_root  <<<dim3(1),   dim3(256), 0, stream>>>(l9, WW, Wb, pW, pb, out);
}

// Round 11
// 82.263 us; speedup vs baseline: 1.0618x; 1.0618x over previous
//
#include <hip/hip_runtime.h>

#define SEQ   8192
#define EMB   64
#define NLEAF 8192
#define KQ    2048          // K per gemm block (quarter of SEQ)
#define KT    64            // K per LDS tile
#define NT    (KQ / KT)     // 32 tiles

typedef __attribute__((ext_vector_type(4))) float        f32x4;
typedef __attribute__((ext_vector_type(4))) unsigned int u32x4;

// ---- bf16 RNE pack: pair (x,y) -> [bf16(x) | bf16(y)<<16] ----
__device__ __forceinline__ unsigned rne_pair(float x, float y) {
    const unsigned ux = __float_as_uint(x), uy = __float_as_uint(y);
    const unsigned rx = (ux + 0x7fffu + ((ux >> 16) & 1u)) >> 16;
    const unsigned ry = (uy + 0x7fffu + ((uy >> 16) & 1u)) & 0xffff0000u;
    return rx | ry;
}

__device__ __forceinline__ void mfma16(f32x4& d, const u32x4 a, const u32x4 b) {
    asm("v_mfma_f32_16x16x32_bf16 %0, %1, %2, %0" : "+v"(d) : "v"(a), "v"(b));
}

// Read 8 consecutive-k f32 from a swizzled 64x64 f32 LDS tile (256B rows,
// 16B chunk index XORed with row&7), emit one RNE bf16 fragment.
__device__ __forceinline__ u32x4 frag_rne(const float* buf, int row, int kk) {
    const int c = kk >> 2;          // even chunk index
    const int s = row & 7;
    const char* base = (const char*)buf + row * 256;
    const f32x4 v0 = *(const f32x4*)(base + 16 * (c ^ s));
    const f32x4 v1 = *(const f32x4*)(base + 16 * ((c + 1) ^ s));
    u32x4 h;
    h[0] = rne_pair(v0.x, v0.y);
    h[1] = rne_pair(v0.z, v0.w);
    h[2] = rne_pair(v1.x, v1.y);
    h[3] = rne_pair(v1.z, v1.w);
    return h;
}

// async global->LDS, 16B per lane; offset immediate ALWAYS 0 (R4 lesson).
#define GLDS16(gp, lp) \
    __builtin_amdgcn_global_load_lds( \
        (const __attribute__((address_space(1))) void*)(gp), \
        (__attribute__((address_space(3))) void*)(lp), 16, 0, 0)

// ============================================================================
// K0: W [64][8192] f32 -> bf16 RNE per-tile LDS images (8KB each, 64 rows x
// 128B, content chunk = chsw ^ (row&7)). R5-identical.
// ============================================================================
__global__ __launch_bounds__(256) void k_cvtW(const float* __restrict__ W,
                                              unsigned* __restrict__ Wt)
{
    const int gid  = blockIdx.x * 256 + threadIdx.x;   // 65536 = 4*32*64*8
    const int chsw = gid & 7;
    const int row  = (gid >> 3) & 63;
    const int t    = (gid >> 9) & 31;
    const int q    = gid >> 14;
    const int c    = chsw ^ (row & 7);
    const float* src = W + (size_t)row * SEQ + q * KQ + t * KT + c * 8;
    const f32x4 a = *(const f32x4*)(src);
    const f32x4 b = *(const f32x4*)(src + 4);
    u32x4 v;
    v[0] = rne_pair(a.x, a.y);
    v[1] = rne_pair(a.z, a.w);
    v[2] = rne_pair(b.x, b.y);
    v[3] = rne_pair(b.z, b.w);
    u32x4* dst = (u32x4*)(Wt + ((q * 32 + t) * 512 + row * 8 + chsw) * 4);
    *dst = v;
}

// ============================================================================
// K1: leaf embedding GEMM -- R5 champion verbatim (82.9us, absmax 0).
// grid 512 = 128 leaf-groups x 4 k-quarters; block 256 (4 waves); 72KB LDS;
// 2 blocks/CU; 3-buffer depth-2 pipeline, counted vmcnt(6).
// ============================================================================
__global__ __launch_bounds__(256, 2) void k_gemm(
        const float* __restrict__ A, const char* __restrict__ Wt,
        float* __restrict__ P)
{
    __shared__ float sA[3][64 * 64];        // f32 A tiles, swizzled rows
    __shared__ char  sW[3][8192];           // bf16 W tile images

    const int tid  = threadIdx.x;
    const int lane = tid & 63;
    const int wid  = tid >> 6;

    const int g     = blockIdx.x >> 2;   // leaf group (64 leaves)
    const int q     = blockIdx.x & 3;    // k quarter
    const int gl0   = g * 64;
    const int kbase = q * KQ;

    const int lr = lane >> 4;            // row within 4-row group (A staging)
    const int lc = lane & 15;            // 16B chunk within 256B row

    const float* pA0;
    const float* pA1;
    const float* pA2;
    const float* pA3;
    {
        const int r0 = wid * 16 + 0 * 4 + lr;
        const int r1 = wid * 16 + 1 * 4 + lr;
        const int r2 = wid * 16 + 2 * 4 + lr;
        const int r3 = wid * 16 + 3 * 4 + lr;
        pA0 = A + (size_t)(gl0 + r0) * SEQ + kbase + (lc ^ (r0 & 7)) * 4;
        pA1 = A + (size_t)(gl0 + r1) * SEQ + kbase + (lc ^ (r1 & 7)) * 4;
        pA2 = A + (size_t)(gl0 + r2) * SEQ + kbase + (lc ^ (r2 & 7)) * 4;
        pA3 = A + (size_t)(gl0 + r3) * SEQ + kbase + (lc ^ (r3 & 7)) * 4;
    }
    const char* pW = Wt + (size_t)(q * 32) * 8192 + (2 * wid) * 1024 + lane * 16;

    const int fr = lane & 15;
    const int fq = lane >> 4;

    f32x4 acc0 = {0.f, 0.f, 0.f, 0.f};
    f32x4 acc1 = {0.f, 0.f, 0.f, 0.f};
    f32x4 acc2 = {0.f, 0.f, 0.f, 0.f};
    f32x4 acc3 = {0.f, 0.f, 0.f, 0.f};

#define STAGE(bi_) do { \
    char* wdst = (char*)&sW[bi_][0] + 2 * wid * 1024; \
    GLDS16(pW, wdst); \
    GLDS16(pW + 1024, wdst + 1024); \
    pW += 8192; \
    GLDS16(pA0, &sA[bi_][(wid * 16 + 0) * 64]); \
    GLDS16(pA1, &sA[bi_][(wid * 16 + 4) * 64]); \
    GLDS16(pA2, &sA[bi_][(wid * 16 + 8) * 64]); \
    GLDS16(pA3, &sA[bi_][(wid * 16 + 12) * 64]); \
    pA0 += KT; pA1 += KT; pA2 += KT; pA3 += KT; \
} while (0)

#define COMPUTE(bi_) do { \
    const float* bufA_ = &sA[bi_][0]; \
    const char*  bufW_ = &sW[bi_][0]; \
    _Pragma("unroll") \
    for (int k32 = 0; k32 < 2; ++k32) { \
        const u32x4 af = frag_rne(bufA_, wid * 16 + fr, k32 * 32 + fq * 8); \
        const int baddr = fr * 128 + 16 * ((k32 * 4 + fq) ^ (fr & 7)); \
        const u32x4 b0 = *(const u32x4*)(bufW_ + baddr); \
        const u32x4 b1 = *(const u32x4*)(bufW_ + 2048 + baddr); \
        const u32x4 b2 = *(const u32x4*)(bufW_ + 4096 + baddr); \
        const u32x4 b3 = *(const u32x4*)(bufW_ + 6144 + baddr); \
        mfma16(acc0, af, b0); \
        mfma16(acc1, af, b1); \
        mfma16(acc2, af, b2); \
        mfma16(acc3, af, b3); \
    } \
} while (0)

    STAGE(0);
    STAGE(1);

    int bcur = 0, bnxt = 1, bfut = 2;
    #pragma unroll 1
    for (int t = 0; t < NT; ++t) {
        if (t + 1 < NT) asm volatile("s_waitcnt vmcnt(6)" ::: "memory");
        else            asm volatile("s_waitcnt vmcnt(0)" ::: "memory");
        __builtin_amdgcn_s_barrier();
        __builtin_amdgcn_sched_barrier(0);
        if (t + 2 < NT) STAGE(bfut);
        COMPUTE(bcur);
        const int tmp = bcur; bcur = bnxt; bnxt = bfut; bfut = tmp;
    }

#undef STAGE
#undef COMPUTE

    float* Pq = P + (size_t)q * NLEAF * EMB;
    const int row0 = gl0 + wid * 16 + fq * 4;
    #pragma unroll
    for (int r = 0; r < 4; ++r) {
        Pq[(size_t)(row0 + r) * EMB +  0 + fr] = acc0[r];
        Pq[(size_t)(row0 + r) * EMB + 16 + fr] = acc1[r];
        Pq[(size_t)(row0 + r) * EMB + 32 + fr] = acc2[r];
        Pq[(size_t)(row0 + r) * EMB + 48 + fr] = acc3[r];
    }
}

// ============================================================================
// Tree (R5-verbatim champion tail). fp32 exact.
// ============================================================================
__device__ __forceinline__ void load_Wt(float (*Wt)[132],
                                        const float* __restrict__ WW, int tid) {
    const int e  = tid >> 2;
    const int c0 = (tid & 3) * 32;
    #pragma unroll
    for (int j = 0; j < 32; j += 4)
        *(f32x4*)&Wt[e][c0 + j] = *(const f32x4*)&WW[e * 128 + c0 + j];
}

__device__ __forceinline__ float hsum4(const f32x4 a) {
    return a.x + a.y + a.z + a.w;
}

__device__ __forceinline__ float* tree_levels(float* bufA, float* bufB,
        const float (*Wt)[132], float wb, int n0, int nlv, int tid)
{
    const int lane = tid & 63;
    const int wid  = tid >> 6;
    float* src = bufA;
    float* dst = bufB;
    int n = n0;
    for (int lvl = 0; lvl < nlv; ++lvl) {
        const int nodes = n >> 1;
        for (int base = wid * 4; base < nodes; base += 16) {
            const int cnt = (nodes - base < 4) ? (nodes - base) : 4;
            if (cnt == 4) {
                f32x4 ac0 = {0.f,0.f,0.f,0.f}, ac1 = ac0, ac2 = ac0, ac3 = ac0;
                const float* x0 = src + (2 * (base + 0)) * 68;
                const float* x1 = src + (2 * (base + 1)) * 68;
                const float* x2 = src + (2 * (base + 2)) * 68;
                const float* x3 = src + (2 * (base + 3)) * 68;
                #pragma unroll
                for (int j = 0; j < 32; ++j) {
                    const f32x4 w4 = *(const f32x4*)&Wt[lane][4 * j];
                    const int off = (j < 16) ? (4 * j) : (68 + 4 * (j - 16));
                    ac0 += w4 * *(const f32x4*)(x0 + off);
                    ac1 += w4 * *(const f32x4*)(x1 + off);
                    ac2 += w4 * *(const f32x4*)(x2 + off);
                    ac3 += w4 * *(const f32x4*)(x3 + off);
                }
                dst[(base + 0) * 68 + lane] = fmaxf(wb + hsum4(ac0), 0.f);
                dst[(base + 1) * 68 + lane] = fmaxf(wb + hsum4(ac1), 0.f);
                dst[(base + 2) * 68 + lane] = fmaxf(wb + hsum4(ac2), 0.f);
                dst[(base + 3) * 68 + lane] = fmaxf(wb + hsum4(ac3), 0.f);
            } else {
                for (int u = 0; u < cnt; ++u) {
                    f32x4 ac = {0.f, 0.f, 0.f, 0.f};
                    const float* x = src + (2 * (base + u)) * 68;
                    #pragma unroll
                    for (int j = 0; j < 32; ++j) {
                        const f32x4 w4 = *(const f32x4*)&Wt[lane][4 * j];
                        const int off = (j < 16) ? (4 * j) : (68 + 4 * (j - 16));
                        ac += w4 * *(const f32x4*)(x + off);
                    }
                    dst[(base + u) * 68 + lane] = fmaxf(wb + hsum4(ac), 0.f);
                }
            }
        }
        __syncthreads();
        float* tswp = src; src = dst; dst = tswp;
        n = nodes;
    }
    return src;   // root row after final swap
}

// K2: combine 4 K-quarter partials + bias + relu, then tree levels 1..5.
__global__ __launch_bounds__(256) void k_tree32(const float* __restrict__ P,
        const float* __restrict__ eb, const float* __restrict__ WW,
        const float* __restrict__ Wb, float* __restrict__ roots)
{
    __shared__ float hA[32][68];
    __shared__ float hB[16][68];
    __shared__ float Wt[64][132];
    const int tid = threadIdx.x;
    const int b   = blockIdx.x;
    load_Wt(Wt, WW, tid);
    {
        const int lf = tid >> 3;
        const int e0 = (tid & 7) * 8;
        const size_t base = (size_t)(b * 32 + lf) * EMB + e0;
        f32x4 s0 = *(const f32x4*)&P[base];
        f32x4 s1 = *(const f32x4*)&P[base + 4];
        s0 += *(const f32x4*)&P[(size_t)1 * NLEAF * EMB + base];
        s1 += *(const f32x4*)&P[(size_t)1 * NLEAF * EMB + base + 4];
        s0 += *(const f32x4*)&P[(size_t)2 * NLEAF * EMB + base];
        s1 += *(const f32x4*)&P[(size_t)2 * NLEAF * EMB + base + 4];
        s0 += *(const f32x4*)&P[(size_t)3 * NLEAF * EMB + base];
        s1 += *(const f32x4*)&P[(size_t)3 * NLEAF * EMB + base + 4];
        s0 += *(const f32x4*)&eb[e0];
        s1 += *(const f32x4*)&eb[e0 + 4];
        s0.x = fmaxf(s0.x, 0.f); s0.y = fmaxf(s0.y, 0.f);
        s0.z = fmaxf(s0.z, 0.f); s0.w = fmaxf(s0.w, 0.f);
        s1.x = fmaxf(s1.x, 0.f); s1.y = fmaxf(s1.y, 0.f);
        s1.z = fmaxf(s1.z, 0.f); s1.w = fmaxf(s1.w, 0.f);
        *(f32x4*)&hA[lf][e0]     = s0;
        *(f32x4*)&hA[lf][e0 + 4] = s1;
    }
    const float wb = Wb[tid & 63];
    __syncthreads();
    float* root = tree_levels(&hA[0][0], &hB[0][0], Wt, wb, 32, 5, tid);
    if (tid < 64) roots[b * 64 + tid] = root[tid];
}

// K3a: 16 roots -> 1 (levels 6..9). grid 16.
__global__ __launch_bounds__(256) void k_tree16(const float* __restrict__ in,
        const float* __restrict__ WW, const float* __restrict__ Wb,
        float* __restrict__ outv)
{
    __shared__ float hA[32][68];
    __shared__ float hB[16][68];
    __shared__ float Wt[64][132];
    const int tid = threadIdx.x;
    load_Wt(Wt, WW, tid);
    {
        const int r  = tid >> 4;
        const int e0 = (tid & 15) * 4;
        *(f32x4*)&hA[r][e0] =
            *(const f32x4*)&in[(size_t)(blockIdx.x * 16 + r) * EMB + e0];
    }
    const float wb = Wb[tid & 63];
    __syncthreads();
    float* root = tree_levels(&hA[0][0], &hB[0][0], Wt, wb, 16, 4, tid);
    if (tid < 64) outv[blockIdx.x * 64 + tid] = root[tid];
}

// K3b: 16 -> 1 (levels 10..13) + projection. grid 1.
__global__ __launch_bounds__(256) void k_root(const float* __restrict__ in,
        const float* __restrict__ WW, const float* __restrict__ Wb,
        const float* __restrict__ pW, const float* __restrict__ pb,
        float* __restrict__ out)
{
    __shared__ float hA[32][68];
    __shared__ float hB[16][68];
    __shared__ float Wt[64][132];
    const int tid = threadIdx.x;
    load_Wt(Wt, WW, tid);
    {
        const int r  = tid >> 4;
        const int e0 = (tid & 15) * 4;
        *(f32x4*)&hA[r][e0] = *(const f32x4*)&in[(size_t)r * EMB + e0];
    }
    const float wb = Wb[tid & 63];
    __syncthreads();
    float* root = tree_levels(&hA[0][0], &hB[0][0], Wt, wb, 16, 4, tid);
    if (tid < 64) {
        const float hv = root[tid];
        float t0 = hv * pW[tid];
        float t1 = hv * pW[64 + tid];
        #pragma unroll
        for (int off = 32; off > 0; off >>= 1) {
            t0 += __shfl_down(t0, off);
            t1 += __shfl_down(t1, off);
        }
        if (tid == 0) { out[0] = t0 + pb[0]; out[1] = t1 + pb[1]; }
    }
}

extern "C" void kernel_launch(void* const* d_in, const int* in_sizes, int n_in,
                              void* d_out, int out_size, void* d_ws, size_t ws_size,
                              hipStream_t stream)
{
    const float* A  = (const float*)d_in[0];   // leaf_seqs [8192][8192]
    const float* eW = (const float*)d_in[1];   // emb_W     [64][8192]
    const float* eb = (const float*)d_in[2];   // emb_b     [64]
    const float* WW = (const float*)d_in[3];   // W_W       [64][128]
    const float* Wb = (const float*)d_in[4];   // W_b       [64]
    const float* pW = (const float*)d_in[5];   // proj_W    [2][64]
    const float* pb = (const float*)d_in[6];   // proj_b    [2]
    float* out = (float*)d_out;

    float* P     = (float*)d_ws;                       // [4][8192][64] f32 = 8MB
    float* roots = P + (size_t)4 * NLEAF * EMB;        // [256][64]
    float* l9    = roots + 256 * EMB;                  // [16][64]
    char*  Wtil  = (char*)d_ws + (size_t)16 * 1024 * 1024;  // 1MB bf16 tile imgs

    k_cvtW  <<<dim3(256), dim3(256), 0, stream>>>(eW, (unsigned*)Wtil);
    k_gemm  <<<dim3(512), dim3(256), 0, stream>>>(A, Wtil, P);
    k_tree32<<<dim3(256), dim3(256), 0, stream>>>(P, eb, WW, Wb, roots);
    k_tree16<<<dim3(16),  dim3(256), 0, stream>>>(roots, WW, Wb, l9);
    k_root  <<<dim3(1),   dim3(256), 0, stream>>>(l9, WW, Wb, pW, pb, out);
}